// Round 12
// baseline (97.550 us; speedup 1.0000x reference)
//
#include <hip/hip_runtime.h>
#include <hip/hip_bf16.h>

#define DEV __device__ __forceinline__

typedef __attribute__((ext_vector_type(8))) short short8;
typedef __attribute__((ext_vector_type(8))) unsigned short ushort8;
typedef __attribute__((ext_vector_type(4))) float f32x4;
typedef __attribute__((ext_vector_type(2))) unsigned int uint2v;

// ---------- helpers ----------
DEV unsigned short f2bf(float f) {
    unsigned u = __float_as_uint(f);
    unsigned r = u + 0x7fffu + ((u >> 16) & 1u);
    return (unsigned short)(r >> 16);
}
DEV unsigned cvt_pk_bf16(float lo, float hi) {
    unsigned r;
    asm("v_cvt_pk_bf16_f32 %0, %1, %2" : "=v"(r) : "v"(lo), "v"(hi));
    return r;
}
#define GLDS16(gp, lp)                                                              \
    __builtin_amdgcn_global_load_lds(                                               \
        (const __attribute__((address_space(1))) void*)(gp),                        \
        (__attribute__((address_space(3))) void*)(lp), 16, 0, 0)

// Fragment-major bf16 layout for all intermediates:
//   token group g = 16 tokens; element (tok=q15, feature f) at
//   group*1024 + (nt*64 + q15*4 + h_p)*4 + rg,  nt=f>>4, h_p=(f>>2)&3, rg=f&3.
// qh groups: (bl*6+nn)*7 + t  (t=0..6, rows r=t*16+q15, pad r>=100)   -> 16800 groups
// kh/vh groups: bl*6 + nn     (kn = nn*16 + q15)                      ->  2400 groups
// am groups: bl*7 + t                                                  ->  2800 groups

// ---------- K0: fold LN affine / scale / gate into FRAGMENT-ORDERED bf16 weights ----
__global__ __launch_bounds__(128) void prep_kernel(
    const float* __restrict__ wq, const float* __restrict__ wk,
    const float* __restrict__ wv, const float* __restrict__ wp,
    const float* __restrict__ ln_q_g, const float* __restrict__ ln_q_b,
    const float* __restrict__ ln_k_g, const float* __restrict__ ln_k_b,
    const float* __restrict__ ln_v_g, const float* __restrict__ ln_v_b,
    const float* __restrict__ bq, const float* __restrict__ bk,
    const float* __restrict__ bv, const float* __restrict__ bp,
    const float* __restrict__ head_gate,
    unsigned short* __restrict__ Wt, float* __restrict__ b2)
{
    const int set = blockIdx.x / 9, sub = blockIdx.x % 9;
    const float* W    = set == 0 ? wq : set == 1 ? wk : set == 2 ? wv : wp;
    const float* g    = set == 0 ? ln_q_g : set == 1 ? ln_k_g : ln_v_g;
    const float* e    = set == 0 ? ln_q_b : set == 1 ? ln_k_b : ln_v_b;
    const float* bias = set == 0 ? bq : set == 1 ? bk : set == 2 ? bv : bp;
    const int mode = set == 0 ? 2 : (set == 3 ? 0 : 1);
    const float scale = 0.17677669529663687f; // 32^-0.5

    if (sub == 0) {
        const int col = threadIdx.x;
        float sg = (mode == 2) ? scale * head_gate[col >> 5] : 1.f;
        float esum = 0.f;
        if (mode >= 1) {
#pragma unroll 8
            for (int k = 0; k < 128; ++k) esum += e[k] * W[k * 128 + col];
        }
        b2[set * 128 + col] = (bias[col] + esum) * sg;
    } else {
        const int k = threadIdx.x;            // 0..127
        const float gk = (mode >= 1) ? g[k] : 1.f;
        const int kk = k >> 5, h = (k >> 3) & 3, j = k & 7;
#pragma unroll
        for (int c = 0; c < 16; ++c) {
            int col = (sub - 1) * 16 + c;
            int nt = col >> 4, q15 = col & 15;
            float sg = (mode == 2) ? scale * head_gate[col >> 5] : 1.f;
            long idx = set * 16384 + (((nt * 4 + kk) * 64 + q15 * 4 + h) << 3) + j;
            Wt[idx] = f2bf(W[k * 128 + col] * gk * sg);
        }
    }
}

// ---------- K1: LN + 128x128 projection via MFMA (q, k, v merged) ----------
// 5400 blocks, 1 group/wave, NO barrier. Src loaded COALESCED (1KB/instr) into a
// per-wave swizzled LDS tile (32 KB total). Weight fragments read DIRECTLY from
// global fragment-major Wt (1KB coalesced per instr, L1-resident: one set = 32KB).
__global__ __launch_bounds__(256) void qkv_proj_mfma(
    const float* __restrict__ qsrc, const float* __restrict__ ksrc, const float* __restrict__ vsrc,
    const unsigned short* __restrict__ WtAll, const float* __restrict__ b2All,
    unsigned short* __restrict__ qh, unsigned short* __restrict__ kh, unsigned short* __restrict__ vh)
{
    __shared__ float SrcT[4][2048];         // 32 KB: per-wave [16][128] swizzled

    const int bid = blockIdx.x;
    const int tid = threadIdx.x;
    const int w = tid >> 6, lane = tid & 63;
    const int q15 = lane & 15, h = lane >> 4;

    const float* src; unsigned short* dst; int set, isQ, grp;
    if (bid < 4200)      { src = qsrc; dst = qh; set = 0; isQ = 1; grp = bid * 4 + w; }
    else if (bid < 4800) { src = ksrc; dst = kh; set = 1; isQ = 0; grp = (bid - 4200) * 4 + w; }
    else                 { src = vsrc; dst = vh; set = 2; isQ = 0; grp = (bid - 4800) * 4 + w; }
    const unsigned short* WtF = WtAll + set * 16384;
    const float* b2 = b2All + set * 128;

    // group's first source row + clamp bound
    long r0; int maxrr;
    if (isQ) {
        int wv6 = grp / 7, t = grp % 7;
        int bl = wv6 / 6, nn = wv6 % 6;
        int b = bl / 100, l = bl % 100;
        r0 = ((long)(b * 6 + nn) * 100 + l) * 100 + t * 16;
        maxrr = (t == 6) ? 3 : 15;          // clamp pad rows to row 99
    } else {
        int bl = grp / 6, nn = grp % 6;
        int b = bl / 100, l = bl % 100;
        r0 = ((long)(b * 6 + nn) * 100 + l) * 16;
        maxrr = 15;
    }

    // coalesced load: instr i covers rows {2i, 2i+1}, 1KB contiguous per wave
    {
        const int half = lane >> 5, li = lane & 31;
        float* st = SrcT[w];
#pragma unroll
        for (int i = 0; i < 8; ++i) {
            int rr = 2 * i + half;
            int rrc = rr > maxrr ? maxrr : rr;
            f32x4 v = *(const f32x4*)(src + (r0 + rrc) * 128 + li * 4);
            *(f32x4*)&st[rr * 128 + ((li * 4) ^ ((rr & 7) << 2))] = v;
        }
    }

    // fragment reads from LDS (row q15, cols kk*32+h*8..+7)
    float x[4][8];
    {
        const float* st = SrcT[w];
        const int sw = (q15 & 7) << 2;
#pragma unroll
        for (int kk = 0; kk < 4; ++kk) {
            int c0 = kk * 32 + h * 8;
            f32x4 a = *(const f32x4*)&st[q15 * 128 + (c0 ^ sw)];
            f32x4 b = *(const f32x4*)&st[q15 * 128 + ((c0 + 4) ^ sw)];
            x[kk][0] = a[0]; x[kk][1] = a[1]; x[kk][2] = a[2]; x[kk][3] = a[3];
            x[kk][4] = b[0]; x[kk][5] = b[1]; x[kk][6] = b[2]; x[kk][7] = b[3];
        }
    }

    float s = 0.f, s2 = 0.f;
#pragma unroll
    for (int kk = 0; kk < 4; ++kk)
#pragma unroll
        for (int j = 0; j < 8; ++j) { s += x[kk][j]; s2 += x[kk][j] * x[kk][j]; }
    s  += __shfl_xor(s, 16);  s  += __shfl_xor(s, 32);
    s2 += __shfl_xor(s2, 16); s2 += __shfl_xor(s2, 32);
    const float mean = s * (1.f / 128.f);
    const float var  = s2 * (1.f / 128.f) - mean * mean;
    const float rs  = rsqrtf(var + 1e-5f);
    const float mrs = -mean * rs;

    short8 xf[4];
#pragma unroll
    for (int kk = 0; kk < 4; ++kk) {
        union { unsigned u[4]; short8 s8; } cv;
#pragma unroll
        for (int d = 0; d < 4; ++d)
            cv.u[d] = cvt_pk_bf16(fmaf(x[kk][2 * d], rs, mrs), fmaf(x[kk][2 * d + 1], rs, mrs));
        xf[kk] = cv.s8;
    }

    f32x4 acc[8];
#pragma unroll
    for (int nt = 0; nt < 8; ++nt)
        acc[nt] = *(const f32x4*)(b2 + nt * 16 + h * 4);

    // weight fragments straight from global (coalesced 1KB/instr, L1-resident)
#pragma unroll
    for (int kk = 0; kk < 4; ++kk)
#pragma unroll
        for (int nt = 0; nt < 8; ++nt) {
            short8 wf = *(const short8*)&WtF[(((nt * 4 + kk) * 64) + lane) * 8];
            acc[nt] = __builtin_amdgcn_mfma_f32_16x16x32_bf16(wf, xf[kk], acc[nt], 0, 0, 0);
        }

    // fragment-major store: contiguous 512B per nt per wave
    unsigned short* og = dst + (long)grp * 1024;
#pragma unroll
    for (int nt = 0; nt < 8; ++nt) {
        uint2v pk;
        pk.x = cvt_pk_bf16(acc[nt][0], acc[nt][1]);
        pk.y = cvt_pk_bf16(acc[nt][2], acc[nt][3]);
        *(uint2v*)(og + (nt * 64 + q15 * 4 + h) * 4) = pk;
    }
}

// ---------- K2: MFMA windowed attention per (b,l,head,half) ----------
__global__ __launch_bounds__(256, 3) void attn_mfma_kernel(
    const unsigned short* __restrict__ qh, const unsigned short* __restrict__ kh,
    const unsigned short* __restrict__ vh, unsigned short* __restrict__ am)
{
    __shared__ unsigned short Vt[32 * 104];        // V^T, row stride 104
    __shared__ unsigned short Pt[4][2][16 * 104];  // per-wave double-buffered P^T

    const int tid = threadIdx.x;
    const int half = blockIdx.x & 1;
    const int m  = (blockIdx.x >> 1) & 3;
    const int bl = blockIdx.x >> 3;
    const int w = tid >> 6, lane = tid & 63;
    const int q15 = lane & 15, h = lane >> 4;
    const int t = half * 4 + w;                    // r-tile 0..7 (7 = inactive)

    const int coff = (((2 * m + (h >> 1)) * 64) + q15 * 4 + 2 * (h & 1)) * 4;

    short8 kf[6];
#pragma unroll
    for (int ntk = 0; ntk < 6; ++ntk)
        kf[ntk] = *(const short8*)(kh + (long)(bl * 6 + ntk) * 1024 + coff);

    {
        const int d = tid & 31, kt0 = tid >> 5;
        const int f = m * 32 + d;
        const int ntv = f >> 4, hp = (f >> 2) & 3, rg = f & 3;
#pragma unroll
        for (int j = 0; j < 12; ++j) {
            int kt = kt0 + 8 * j;
            Vt[d * 104 + kt] =
                vh[(long)(bl * 6 + (kt >> 4)) * 1024 + ((ntv * 64 + (kt & 15) * 4 + hp) << 2) + rg];
        }
    }
    __syncthreads();

    short8 vf[2][3];
#pragma unroll
    for (int dt = 0; dt < 2; ++dt)
#pragma unroll
        for (int ks = 0; ks < 3; ++ks)
            vf[dt][ks] = *(const short8*)(Vt + (dt * 16 + q15) * 104 + ks * 32 + h * 8);

    if (t >= 7) return;

    const long qgBase = (long)(bl * 6) * 7 * 1024;

    f32x4 o0 = {0.f, 0.f, 0.f, 0.f}, o1 = {0.f, 0.f, 0.f, 0.f};

#pragma unroll
    for (int nn = 0; nn < 6; ++nn) {
        unsigned short* ptw = &Pt[w][nn & 1][0];

        short8 qf = *(const short8*)(qh + qgBase + (long)(nn * 7 + t) * 1024 + coff);

        f32x4 sc[6];
#pragma unroll
        for (int nt = 0; nt < 6; ++nt)
            sc[nt] = __builtin_amdgcn_mfma_f32_16x16x32_bf16(kf[nt], qf, (f32x4){0.f, 0.f, 0.f, 0.f}, 0, 0, 0);

        float p[24];
#pragma unroll
        for (int nt = 0; nt < 6; ++nt)
#pragma unroll
            for (int rg = 0; rg < 4; ++rg)
                p[nt * 4 + rg] = __expf(sc[nt][rg]);

#pragma unroll
        for (int nt = 0; nt < 6; ++nt) {
            uint2v pk;
            pk.x = cvt_pk_bf16(p[nt * 4 + 0], p[nt * 4 + 1]);
            pk.y = cvt_pk_bf16(p[nt * 4 + 2], p[nt * 4 + 3]);
            *(uint2v*)(ptw + q15 * 104 + nt * 16 + h * 4) = pk;
        }

        float s01 = (p[0] + p[1]) + (p[2] + p[3]);
        float s23 = (p[4] + p[5]) + (p[6] + p[7]);
        float s45 = (p[8] + p[9]) + (p[10] + p[11]);
        float s67 = (p[12] + p[13]) + (p[14] + p[15]);
        float s89 = (p[16] + p[17]) + (p[18] + p[19]);
        float sab = (p[20] + p[21]) + (p[22] + p[23]);
        float sum = ((s01 + s23) + (s45 + s67)) + (s89 + sab);
        sum += __shfl_xor(sum, 16);
        sum += __shfl_xor(sum, 32);
        const float inv = __builtin_amdgcn_rcpf(6.f * sum);

        f32x4 t0 = {0.f, 0.f, 0.f, 0.f}, t1 = {0.f, 0.f, 0.f, 0.f};
#pragma unroll
        for (int ks = 0; ks < 3; ++ks) {
            short8 pf = *(const short8*)(ptw + q15 * 104 + ks * 32 + h * 8);
            t0 = __builtin_amdgcn_mfma_f32_16x16x32_bf16(vf[0][ks], pf, t0, 0, 0, 0);
            t1 = __builtin_amdgcn_mfma_f32_16x16x32_bf16(vf[1][ks], pf, t1, 0, 0, 0);
        }

#pragma unroll
        for (int rg = 0; rg < 4; ++rg) {
            o0[rg] += t0[rg] * inv;
            o1[rg] += t1[rg] * inv;
        }
    }

    {
        unsigned short* og = am + (long)(bl * 7 + t) * 1024;
        uint2v a0, a1;
        a0.x = cvt_pk_bf16(o0[0], o0[1]);
        a0.y = cvt_pk_bf16(o0[2], o0[3]);
        a1.x = cvt_pk_bf16(o1[0], o1[1]);
        a1.y = cvt_pk_bf16(o1[2], o1[3]);
        *(uint2v*)(og + ((2 * m) * 64 + q15 * 4 + h) * 4) = a0;
        *(uint2v*)(og + ((2 * m + 1) * 64 + q15 * 4 + h) * 4) = a1;
    }
}

// ---------- K3: output projection via MFMA + bias + skip ----------
__global__ __launch_bounds__(256) void out_proj_mfma(
    const unsigned short* __restrict__ am, const unsigned short* __restrict__ WtF,
    const float* __restrict__ b2, const float* __restrict__ skip, float* __restrict__ out)
{
    const int tid = threadIdx.x;
    const int w = tid >> 6, lane = tid & 63;
    const int q15 = lane & 15, h = lane >> 4;
    const int gp = blockIdx.x * 4 + w;
    const int bl = gp / 7, t = gp % 7;
    const int r = t * 16 + q15;
    const long tok = (long)bl * 100 + r;

    short8 xf[4];
#pragma unroll
    for (int kk = 0; kk < 4; ++kk)
        xf[kk] = *(const short8*)(am + (long)gp * 1024 +
                                  (((2 * kk + (h >> 1)) * 64 + q15 * 4 + 2 * (h & 1)) << 2));

    f32x4 acc[8];
#pragma unroll
    for (int nt = 0; nt < 8; ++nt)
        acc[nt] = *(const f32x4*)(b2 + nt * 16 + h * 4);

#pragma unroll
    for (int kk = 0; kk < 4; ++kk)
#pragma unroll
        for (int nt = 0; nt < 8; ++nt) {
            short8 wf = *(const short8*)&WtF[(((nt * 4 + kk) * 64) + lane) * 8];
            acc[nt] = __builtin_amdgcn_mfma_f32_16x16x32_bf16(wf, xf[kk], acc[nt], 0, 0, 0);
        }

    if (r < 100) {
        const float* srow = skip + tok * 128 + h * 4;
        float* orow = out + tok * 128 + h * 4;
#pragma unroll
        for (int nt = 0; nt < 8; ++nt) {
            f32x4 sk = *(const f32x4*)(srow + nt * 16);
            f32x4 o;
#pragma unroll
            for (int rg = 0; rg < 4; ++rg) o[rg] = acc[nt][rg] + sk[rg];
            *(f32x4*)(orow + nt * 16) = o;
        }
    }
}

// ---------- launch ----------
extern "C" void kernel_launch(void* const* d_in, const int* in_sizes, int n_in,
                              void* d_out, int out_size, void* d_ws, size_t ws_size,
                              hipStream_t stream) {
    const float* q        = (const float*)d_in[0];
    const float* k        = (const float*)d_in[1];
    const float* v        = (const float*)d_in[2];
    const float* skip     = (const float*)d_in[3];
    const float* head_gate= (const float*)d_in[4];
    const float* ln_q_g   = (const float*)d_in[5];
    const float* ln_q_b   = (const float*)d_in[6];
    const float* ln_k_g   = (const float*)d_in[7];
    const float* ln_k_b   = (const float*)d_in[8];
    const float* ln_v_g   = (const float*)d_in[9];
    const float* ln_v_b   = (const float*)d_in[10];
    const float* wq       = (const float*)d_in[11];
    const float* bq       = (const float*)d_in[12];
    const float* wk       = (const float*)d_in[13];
    const float* bk       = (const float*)d_in[14];
    const float* wv       = (const float*)d_in[15];
    const float* bv       = (const float*)d_in[16];
    const float* wp       = (const float*)d_in[17];
    const float* bp       = (const float*)d_in[18];
    float* out = (float*)d_out;

    char* ws = (char*)d_ws;
    unsigned short* qh = (unsigned short*)(ws);               // 16800*2048 = 34,406,400 B
    unsigned short* kh = (unsigned short*)(ws + 34406400);    //  2400*2048 =  4,915,200 B
    unsigned short* vh = (unsigned short*)(ws + 39321600);    //  4,915,200 B
    unsigned short* am = (unsigned short*)(ws + 44236800);    //  2800*2048 =  5,734,400 B
    unsigned short* Wt = (unsigned short*)(ws + 49971200);    //  4*32768 B
    float* b2          = (float*)(ws + 50102272);             //  4*512 B

    prep_kernel<<<36, 128, 0, stream>>>(wq, wk, wv, wp,
                                        ln_q_g, ln_q_b, ln_k_g, ln_k_b, ln_v_g, ln_v_b,
                                        bq, bk, bv, bp, head_gate, Wt, b2);
    qkv_proj_mfma<<<5400, 256, 0, stream>>>(q, k, v, Wt, b2, qh, kh, vh);
    attn_mfma_kernel<<<3200, 256, 0, stream>>>(qh, kh, vh, am);
    out_proj_mfma<<<700, 256, 0, stream>>>(am, Wt + 3 * 16384, b2 + 3 * 128, skip, out);
}

// Round 13
// 87.725 us; speedup vs baseline: 1.1120x; 1.1120x over previous
//
#include <hip/hip_runtime.h>
#include <hip/hip_bf16.h>

#define DEV __device__ __forceinline__

typedef __attribute__((ext_vector_type(8))) short short8;
typedef __attribute__((ext_vector_type(8))) unsigned short ushort8;
typedef __attribute__((ext_vector_type(4))) float f32x4;
typedef __attribute__((ext_vector_type(2))) unsigned int uint2v;

// ---------- helpers ----------
DEV unsigned short f2bf(float f) {
    unsigned u = __float_as_uint(f);
    unsigned r = u + 0x7fffu + ((u >> 16) & 1u);
    return (unsigned short)(r >> 16);
}
DEV float bf2f(unsigned short h) { return __uint_as_float(((unsigned)h) << 16); }
DEV unsigned cvt_pk_bf16(float lo, float hi) {
    unsigned r;
    asm("v_cvt_pk_bf16_f32 %0, %1, %2" : "=v"(r) : "v"(lo), "v"(hi));
    return r;
}
#define GLDS16(gp, lp)                                                              \
    __builtin_amdgcn_global_load_lds(                                               \
        (const __attribute__((address_space(1))) void*)(gp),                        \
        (__attribute__((address_space(3))) void*)(lp), 16, 0, 0)

// Fragment-major bf16 layout for all intermediates:
//   token group g = 16 tokens; element (tok=q15, feature f) at
//   group*1024 + (nt*64 + q15*4 + h_p)*4 + rg,  nt=f>>4, h_p=(f>>2)&3, rg=f&3.
// qh groups: (bl*6+nn)*7 + t (pad rows dup row 99) -> 16800 groups
// kh/vh groups: bl*6 + nn                           ->  2400 groups
// am groups: bl*7 + t                               ->  2800 groups

// ---------- K0: fold LN affine / scale / gate into FRAGMENT-ORDERED bf16 weights ----
__global__ __launch_bounds__(128) void prep_kernel(
    const float* __restrict__ wq, const float* __restrict__ wk,
    const float* __restrict__ wv, const float* __restrict__ wp,
    const float* __restrict__ ln_q_g, const float* __restrict__ ln_q_b,
    const float* __restrict__ ln_k_g, const float* __restrict__ ln_k_b,
    const float* __restrict__ ln_v_g, const float* __restrict__ ln_v_b,
    const float* __restrict__ bq, const float* __restrict__ bk,
    const float* __restrict__ bv, const float* __restrict__ bp,
    const float* __restrict__ head_gate,
    unsigned short* __restrict__ Wt, float* __restrict__ b2)
{
    const int set = blockIdx.x / 9, sub = blockIdx.x % 9;
    const float* W    = set == 0 ? wq : set == 1 ? wk : set == 2 ? wv : wp;
    const float* g    = set == 0 ? ln_q_g : set == 1 ? ln_k_g : ln_v_g;
    const float* e    = set == 0 ? ln_q_b : set == 1 ? ln_k_b : ln_v_b;
    const float* bias = set == 0 ? bq : set == 1 ? bk : set == 2 ? bv : bp;
    const int mode = set == 0 ? 2 : (set == 3 ? 0 : 1);
    const float scale = 0.17677669529663687f; // 32^-0.5

    if (sub == 0) {
        const int col = threadIdx.x;
        float sg = (mode == 2) ? scale * head_gate[col >> 5] : 1.f;
        float esum = 0.f;
        if (mode >= 1) {
#pragma unroll 8
            for (int k = 0; k < 128; ++k) esum += e[k] * W[k * 128 + col];
        }
        b2[set * 128 + col] = (bias[col] + esum) * sg;
    } else {
        const int k = threadIdx.x;            // 0..127
        const float gk = (mode >= 1) ? g[k] : 1.f;
        const int kk = k >> 5, h = (k >> 3) & 3, j = k & 7;
#pragma unroll
        for (int c = 0; c < 16; ++c) {
            int col = (sub - 1) * 16 + c;
            int nt = col >> 4, q15 = col & 15;
            float sg = (mode == 2) ? scale * head_gate[col >> 5] : 1.f;
            long idx = set * 16384 + (((nt * 4 + kk) * 64 + q15 * 4 + h) << 3) + j;
            Wt[idx] = f2bf(W[k * 128 + col] * gk * sg);
        }
    }
}

// ---------- K1: LN + 128x128 projection via MFMA (q, k, v merged) ----------
// 5400 blocks, 1 group/wave. Src loaded COALESCED (1KB/instr, f32), converted to
// bf16 in regs, staged in per-wave LDS tile [16][132] bf16 (pad row -> conflict-
// light). LN stats computed from bf16 (error ~2^-9, negligible vs threshold).
// Weights staged once per block via global_load_lds (32KB). LDS total 48.5KB ->
// 3 blocks/CU = 12 waves/CU.
__global__ __launch_bounds__(256) void qkv_proj_mfma(
    const float* __restrict__ qsrc, const float* __restrict__ ksrc, const float* __restrict__ vsrc,
    const unsigned short* __restrict__ WtAll, const float* __restrict__ b2All,
    unsigned short* __restrict__ qh, unsigned short* __restrict__ kh, unsigned short* __restrict__ vh)
{
    __shared__ unsigned short WtL[16384];        // 32 KB fragment-major weights
    __shared__ unsigned short SrcT[4][16 * 132]; // 16.5 KB bf16 staged src

    const int bid = blockIdx.x;
    const int tid = threadIdx.x;
    const int w = tid >> 6, lane = tid & 63;
    const int q15 = lane & 15, h = lane >> 4;

    const float* src; unsigned short* dst; int set, isQ, grp;
    if (bid < 4200)      { src = qsrc; dst = qh; set = 0; isQ = 1; grp = bid * 4 + w; }
    else if (bid < 4800) { src = ksrc; dst = kh; set = 1; isQ = 0; grp = (bid - 4200) * 4 + w; }
    else                 { src = vsrc; dst = vh; set = 2; isQ = 0; grp = (bid - 4800) * 4 + w; }
    const unsigned short* WtF = WtAll + set * 16384;
    const float* b2 = b2All + set * 128;

    // async stage weights -> LDS (16B/lane, linear dest)
#pragma unroll
    for (int i = 0; i < 8; ++i)
        GLDS16(WtF + i * 2048 + tid * 8, &WtL[i * 2048 + w * 512]);

    // group's first source row + clamp bound
    long r0; int maxrr;
    if (isQ) {
        int wv6 = grp / 7, t = grp % 7;
        int bl = wv6 / 6, nn = wv6 % 6;
        int b = bl / 100, l = bl % 100;
        r0 = ((long)(b * 6 + nn) * 100 + l) * 100 + t * 16;
        maxrr = (t == 6) ? 3 : 15;          // clamp pad rows to row 99
    } else {
        int bl = grp / 6, nn = grp % 6;
        int b = bl / 100, l = bl % 100;
        r0 = ((long)(b * 6 + nn) * 100 + l) * 16;
        maxrr = 15;
    }

    // coalesced f32 load (1KB/instr, 2 rows) -> bf16 -> LDS
    {
        const int half = lane >> 5, li = lane & 31;
        unsigned short* st = SrcT[w];
#pragma unroll
        for (int i = 0; i < 8; ++i) {
            int rr = 2 * i + half;
            int rrc = rr > maxrr ? maxrr : rr;
            f32x4 v = *(const f32x4*)(src + (r0 + rrc) * 128 + li * 4);
            uint2v c;
            c.x = cvt_pk_bf16(v[0], v[1]);
            c.y = cvt_pk_bf16(v[2], v[3]);
            *(uint2v*)&st[rr * 132 + li * 4] = c;
        }
    }

    // fragment reads from LDS (row q15, cols kk*32+h*8..+7), unpack for stats
    short8 xr[4];
    float x[4][8];
    {
        const unsigned short* st = SrcT[w];
#pragma unroll
        for (int kk = 0; kk < 4; ++kk) {
            xr[kk] = *(const short8*)&st[q15 * 132 + kk * 32 + h * 8];
#pragma unroll
            for (int j = 0; j < 8; ++j)
                x[kk][j] = bf2f(((unsigned short)xr[kk][j]));
        }
    }

    float s = 0.f, s2 = 0.f;
#pragma unroll
    for (int kk = 0; kk < 4; ++kk)
#pragma unroll
        for (int j = 0; j < 8; ++j) { s += x[kk][j]; s2 += x[kk][j] * x[kk][j]; }
    s  += __shfl_xor(s, 16);  s  += __shfl_xor(s, 32);
    s2 += __shfl_xor(s2, 16); s2 += __shfl_xor(s2, 32);
    const float mean = s * (1.f / 128.f);
    const float var  = s2 * (1.f / 128.f) - mean * mean;
    const float rs  = rsqrtf(var + 1e-5f);
    const float mrs = -mean * rs;

    short8 xf[4];
#pragma unroll
    for (int kk = 0; kk < 4; ++kk) {
        union { unsigned u[4]; short8 s8; } cv;
#pragma unroll
        for (int d = 0; d < 4; ++d)
            cv.u[d] = cvt_pk_bf16(fmaf(x[kk][2 * d], rs, mrs), fmaf(x[kk][2 * d + 1], rs, mrs));
        xf[kk] = cv.s8;
    }

    f32x4 acc[8];
#pragma unroll
    for (int nt = 0; nt < 8; ++nt)
        acc[nt] = *(const f32x4*)(b2 + nt * 16 + h * 4);

    __syncthreads();   // WtL ready (drains global_load_lds)

#pragma unroll
    for (int kk = 0; kk < 4; ++kk)
#pragma unroll
        for (int nt = 0; nt < 8; ++nt) {
            short8 wf = *(const short8*)&WtL[(((nt * 4 + kk) * 64) + lane) * 8];
            acc[nt] = __builtin_amdgcn_mfma_f32_16x16x32_bf16(wf, xf[kk], acc[nt], 0, 0, 0);
        }

    // fragment-major store: contiguous 512B per nt per wave
    unsigned short* og = dst + (long)grp * 1024;
#pragma unroll
    for (int nt = 0; nt < 8; ++nt) {
        uint2v pk;
        pk.x = cvt_pk_bf16(acc[nt][0], acc[nt][1]);
        pk.y = cvt_pk_bf16(acc[nt][2], acc[nt][3]);
        *(uint2v*)(og + (nt * 64 + q15 * 4 + h) * 4) = pk;
    }
}

// ---------- K2: MFMA windowed attention per (b,l,head,half) ----------
__global__ __launch_bounds__(256, 3) void attn_mfma_kernel(
    const unsigned short* __restrict__ qh, const unsigned short* __restrict__ kh,
    const unsigned short* __restrict__ vh, unsigned short* __restrict__ am)
{
    __shared__ unsigned short Vt[32 * 104];        // V^T, row stride 104
    __shared__ unsigned short Pt[4][2][16 * 104];  // per-wave double-buffered P^T

    const int tid = threadIdx.x;
    const int half = blockIdx.x & 1;
    const int m  = (blockIdx.x >> 1) & 3;
    const int bl = blockIdx.x >> 3;
    const int w = tid >> 6, lane = tid & 63;
    const int q15 = lane & 15, h = lane >> 4;
    const int t = half * 4 + w;                    // r-tile 0..7 (7 = inactive)

    const int coff = (((2 * m + (h >> 1)) * 64) + q15 * 4 + 2 * (h & 1)) * 4;

    short8 kf[6];
#pragma unroll
    for (int ntk = 0; ntk < 6; ++ntk)
        kf[ntk] = *(const short8*)(kh + (long)(bl * 6 + ntk) * 1024 + coff);

    {
        const int d = tid & 31, kt0 = tid >> 5;
        const int f = m * 32 + d;
        const int ntv = f >> 4, hp = (f >> 2) & 3, rg = f & 3;
#pragma unroll
        for (int j = 0; j < 12; ++j) {
            int kt = kt0 + 8 * j;
            Vt[d * 104 + kt] =
                vh[(long)(bl * 6 + (kt >> 4)) * 1024 + ((ntv * 64 + (kt & 15) * 4 + hp) << 2) + rg];
        }
    }
    __syncthreads();

    short8 vf[2][3];
#pragma unroll
    for (int dt = 0; dt < 2; ++dt)
#pragma unroll
        for (int ks = 0; ks < 3; ++ks)
            vf[dt][ks] = *(const short8*)(Vt + (dt * 16 + q15) * 104 + ks * 32 + h * 8);

    if (t >= 7) return;

    const long qgBase = (long)(bl * 6) * 7 * 1024;

    f32x4 o0 = {0.f, 0.f, 0.f, 0.f}, o1 = {0.f, 0.f, 0.f, 0.f};

#pragma unroll
    for (int nn = 0; nn < 6; ++nn) {
        unsigned short* ptw = &Pt[w][nn & 1][0];

        short8 qf = *(const short8*)(qh + qgBase + (long)(nn * 7 + t) * 1024 + coff);

        f32x4 sc[6];
#pragma unroll
        for (int nt = 0; nt < 6; ++nt)
            sc[nt] = __builtin_amdgcn_mfma_f32_16x16x32_bf16(kf[nt], qf, (f32x4){0.f, 0.f, 0.f, 0.f}, 0, 0, 0);

        float p[24];
#pragma unroll
        for (int nt = 0; nt < 6; ++nt)
#pragma unroll
            for (int rg = 0; rg < 4; ++rg)
                p[nt * 4 + rg] = __expf(sc[nt][rg]);

#pragma unroll
        for (int nt = 0; nt < 6; ++nt) {
            uint2v pk;
            pk.x = cvt_pk_bf16(p[nt * 4 + 0], p[nt * 4 + 1]);
            pk.y = cvt_pk_bf16(p[nt * 4 + 2], p[nt * 4 + 3]);
            *(uint2v*)(ptw + q15 * 104 + nt * 16 + h * 4) = pk;
        }

        float s01 = (p[0] + p[1]) + (p[2] + p[3]);
        float s23 = (p[4] + p[5]) + (p[6] + p[7]);
        float s45 = (p[8] + p[9]) + (p[10] + p[11]);
        float s67 = (p[12] + p[13]) + (p[14] + p[15]);
        float s89 = (p[16] + p[17]) + (p[18] + p[19]);
        float sab = (p[20] + p[21]) + (p[22] + p[23]);
        float sum = ((s01 + s23) + (s45 + s67)) + (s89 + sab);
        sum += __shfl_xor(sum, 16);
        sum += __shfl_xor(sum, 32);
        const float inv = __builtin_amdgcn_rcpf(6.f * sum);

        f32x4 t0 = {0.f, 0.f, 0.f, 0.f}, t1 = {0.f, 0.f, 0.f, 0.f};
#pragma unroll
        for (int ks = 0; ks < 3; ++ks) {
            short8 pf = *(const short8*)(ptw + q15 * 104 + ks * 32 + h * 8);
            t0 = __builtin_amdgcn_mfma_f32_16x16x32_bf16(vf[0][ks], pf, t0, 0, 0, 0);
            t1 = __builtin_amdgcn_mfma_f32_16x16x32_bf16(vf[1][ks], pf, t1, 0, 0, 0);
        }

#pragma unroll
        for (int rg = 0; rg < 4; ++rg) {
            o0[rg] += t0[rg] * inv;
            o1[rg] += t1[rg] * inv;
        }
    }

    {
        unsigned short* og = am + (long)(bl * 7 + t) * 1024;
        uint2v a0, a1;
        a0.x = cvt_pk_bf16(o0[0], o0[1]);
        a0.y = cvt_pk_bf16(o0[2], o0[3]);
        a1.x = cvt_pk_bf16(o1[0], o1[1]);
        a1.y = cvt_pk_bf16(o1[2], o1[3]);
        *(uint2v*)(og + ((2 * m) * 64 + q15 * 4 + h) * 4) = a0;
        *(uint2v*)(og + ((2 * m + 1) * 64 + q15 * 4 + h) * 4) = a1;
    }
}

// ---------- K3: output projection via MFMA + bias + skip ----------
__global__ __launch_bounds__(256) void out_proj_mfma(
    const unsigned short* __restrict__ am, const unsigned short* __restrict__ WtF,
    const float* __restrict__ b2, const float* __restrict__ skip, float* __restrict__ out)
{
    __shared__ unsigned short WtL[16384];

    const int tid = threadIdx.x;
    const int w = tid >> 6, lane = tid & 63;
    const int q15 = lane & 15, h = lane >> 4;
    const int gp = blockIdx.x * 4 + w;
    const int bl = gp / 7, t = gp % 7;
    const int r = t * 16 + q15;
    const long tok = (long)bl * 100 + r;

#pragma unroll
    for (int i = 0; i < 8; ++i)
        GLDS16(WtF + i * 2048 + tid * 8, &WtL[i * 2048 + w * 512]);

    short8 xf[4];
#pragma unroll
    for (int kk = 0; kk < 4; ++kk)
        xf[kk] = *(const short8*)(am + (long)gp * 1024 +
                                  (((2 * kk + (h >> 1)) * 64 + q15 * 4 + 2 * (h & 1)) << 2));

    f32x4 acc[8];
#pragma unroll
    for (int nt = 0; nt < 8; ++nt)
        acc[nt] = *(const f32x4*)(b2 + nt * 16 + h * 4);

    __syncthreads();

#pragma unroll
    for (int kk = 0; kk < 4; ++kk)
#pragma unroll
        for (int nt = 0; nt < 8; ++nt) {
            short8 wf = *(const short8*)&WtL[(((nt * 4 + kk) * 64) + lane) * 8];
            acc[nt] = __builtin_amdgcn_mfma_f32_16x16x32_bf16(wf, xf[kk], acc[nt], 0, 0, 0);
        }

    if (r < 100) {
        const float* srow = skip + tok * 128 + h * 4;
        float* orow = out + tok * 128 + h * 4;
#pragma unroll
        for (int nt = 0; nt < 8; ++nt) {
            f32x4 sk = *(const f32x4*)(srow + nt * 16);
            f32x4 o;
#pragma unroll
            for (int rg = 0; rg < 4; ++rg) o[rg] = acc[nt][rg] + sk[rg];
            *(f32x4*)(orow + nt * 16) = o;
        }
    }
}

// ---------- launch ----------
extern "C" void kernel_launch(void* const* d_in, const int* in_sizes, int n_in,
                              void* d_out, int out_size, void* d_ws, size_t ws_size,
                              hipStream_t stream) {
    const float* q        = (const float*)d_in[0];
    const float* k        = (const float*)d_in[1];
    const float* v        = (const float*)d_in[2];
    const float* skip     = (const float*)d_in[3];
    const float* head_gate= (const float*)d_in[4];
    const float* ln_q_g   = (const float*)d_in[5];
    const float* ln_q_b   = (const float*)d_in[6];
    const float* ln_k_g   = (const float*)d_in[7];
    const float* ln_k_b   = (const float*)d_in[8];
    const float* ln_v_g   = (const float*)d_in[9];
    const float* ln_v_b   = (const float*)d_in[10];
    const float* wq       = (const float*)d_in[11];
    const float* bq       = (const float*)d_in[12];
    const float* wk       = (const float*)d_in[13];
    const float* bk       = (const float*)d_in[14];
    const float* wv       = (const float*)d_in[15];
    const float* bv       = (const float*)d_in[16];
    const float* wp       = (const float*)d_in[17];
    const float* bp       = (const float*)d_in[18];
    float* out = (float*)d_out;

    char* ws = (char*)d_ws;
    unsigned short* qh = (unsigned short*)(ws);               // 16800*2048 = 34,406,400 B
    unsigned short* kh = (unsigned short*)(ws + 34406400);    //  2400*2048 =  4,915,200 B
    unsigned short* vh = (unsigned short*)(ws + 39321600);    //  4,915,200 B
    unsigned short* am = (unsigned short*)(ws + 44236800);    //  2800*2048 =  5,734,400 B
    unsigned short* Wt = (unsigned short*)(ws + 49971200);    //  4*32768 B
    float* b2          = (float*)(ws + 50102272);             //  4*512 B

    prep_kernel<<<36, 128, 0, stream>>>(wq, wk, wv, wp,
                                        ln_q_g, ln_q_b, ln_k_g, ln_k_b, ln_v_g, ln_v_b,
                                        bq, bk, bv, bp, head_gate, Wt, b2);
    qkv_proj_mfma<<<5400, 256, 0, stream>>>(q, k, v, Wt, b2, qh, kh, vh);
    attn_mfma_kernel<<<3200, 256, 0, stream>>>(qh, kh, vh, am);
    out_proj_mfma<<<700, 256, 0, stream>>>(am, Wt + 3 * 16384, b2 + 3 * 128, skip, out);
}